// Round 15
// baseline (1284.869 us; speedup 1.0000x reference)
//
#include <hip/hip_runtime.h>
#include <math.h>

#define Bb 64
#define Ss 64
#define Hh 1024
#define Vv 32000
#define RD 4032     // 63*64 decoder rows
#define RP 4096     // padded rows
#define NT4 4096    // 4*H
#define ENC_NBLK 64

typedef unsigned short u16;
typedef unsigned long long u64;
typedef __attribute__((ext_vector_type(8))) short bf16x8;
typedef __attribute__((ext_vector_type(4))) float f32x4;

#define MFMA(a, b, c) __builtin_amdgcn_mfma_f32_16x16x32_bf16(a, b, c, 0, 0, 0)

__device__ __forceinline__ u16 f2b(float f) {
  union { float f; unsigned u; } v; v.f = f;
  unsigned r = v.u + 0x7fffu + ((v.u >> 16) & 1u);
  return (u16)(r >> 16);
}
__device__ __forceinline__ float b2f(u16 b) {
  union { unsigned u; float f; } v; v.u = ((unsigned)b) << 16; return v.f;
}
__device__ __forceinline__ float sigf(float x) { return 1.f / (1.f + expf(-x)); }

__device__ __forceinline__ u64 AL(const u64* p) {
  return __hip_atomic_load(p, __ATOMIC_RELAXED, __HIP_MEMORY_SCOPE_AGENT);
}
__device__ __forceinline__ void AS(u64* p, u64 v) {
  __hip_atomic_store(p, v, __ATOMIC_RELAXED, __HIP_MEMORY_SCOPE_AGENT);
}
__device__ __forceinline__ int AL32(const int* p) {
  return __hip_atomic_load(p, __ATOMIC_RELAXED, __HIP_MEMORY_SCOPE_AGENT);
}
__device__ __forceinline__ void AS32(int* p, int v) {
  __hip_atomic_store(p, v, __ATOMIC_RELAXED, __HIP_MEMORY_SCOPE_AGENT);
}

__device__ __forceinline__ void gll16(const void* g, void* l) {
  __builtin_amdgcn_global_load_lds(
      (const __attribute__((address_space(1))) unsigned int*)g,
      (__attribute__((address_space(3))) unsigned int*)l, 16, 0, 0);
}

__global__ void k_fail(float* out) { out[0] = 1e30f; }

// ---- merged prep: weights f32->bf16 (blocks 0..2047, grid-stride) +
// both embedding gathers (blocks 2048..10239) ----
__global__ void k_prep(const float* __restrict__ s0, u16* __restrict__ d0,
                       const float* __restrict__ s1, u16* __restrict__ d1,
                       const float* __restrict__ s2, u16* __restrict__ d2,
                       const float* __restrict__ s3, u16* __restrict__ d3,
                       const float* __restrict__ s4, u16* __restrict__ d4,
                       const float* __restrict__ s5, u16* __restrict__ d5,
                       const int* __restrict__ src_tok, const float* __restrict__ emb_s,
                       u16* __restrict__ out_s,
                       const int* __restrict__ tgt_tok, const float* __restrict__ emb_t,
                       u16* __restrict__ out_t) {
  if (blockIdx.x < 2048) {
    const int A4 = NT4 * Hh / 4;
    const int E4 = Hh * 2048 / 4;
    const int F4 = Vv * Hh / 4;
    const int TOT = 4 * A4 + E4 + F4;
    const int st = 2048 * 256;
    for (int i = blockIdx.x * 256 + threadIdx.x; i < TOT; i += st) {
      const float* sp; u16* dp; int off;
      if (i < A4)            { sp = s0; dp = d0; off = i; }
      else if (i < 2 * A4)   { sp = s1; dp = d1; off = i - A4; }
      else if (i < 3 * A4)   { sp = s2; dp = d2; off = i - 2 * A4; }
      else if (i < 4 * A4)   { sp = s3; dp = d3; off = i - 3 * A4; }
      else if (i < 4 * A4 + E4) { sp = s4; dp = d4; off = i - 4 * A4; }
      else                   { sp = s5; dp = d5; off = i - 4 * A4 - E4; }
      const float4 v = ((const float4*)sp)[off];
      ushort4 o; o.x = f2b(v.x); o.y = f2b(v.y); o.z = f2b(v.z); o.w = f2b(v.w);
      ((ushort4*)dp)[off] = o;
    }
  } else {
    int r = blockIdx.x - 2048;
    const int* tok; const float* emb; u16* outp; int nstep;
    if (r < RP) { tok = src_tok; emb = emb_s; outp = out_s; nstep = 64; }
    else        { r -= RP; tok = tgt_tok; emb = emb_t; outp = out_t; nstep = 63; }
    const int step = r >> 6, b = r & 63;
    const int idx = (step < nstep) ? tok[b * 64 + step] : 0;
    const float4 v = ((const float4*)(emb + (size_t)idx * Hh))[threadIdx.x];
    ushort4 o; o.x = f2b(v.x); o.y = f2b(v.y); o.z = f2b(v.z); o.w = f2b(v.w);
    ((ushort4*)(outp + (size_t)r * Hh))[threadIdx.x] = o;
  }
}

// ---- generic bf16 MFMA GEMM (128^2, 2-barrier) for small shapes.
// EPI==0: fp32 C (+bias).
template<int EPI>
__global__ __launch_bounds__(256)
void k_gemm(const u16* __restrict__ A, const u16* __restrict__ Bm,
            void* __restrict__ C, int M, int N, int K,
            const float* __restrict__ bias) {
  __shared__ __align__(16) u16 As[128 * 64];
  __shared__ __align__(16) u16 Bs[128 * 64];
  const int tid = threadIdx.x;
  const int wave = tid >> 6, lane = tid & 63;
  const int l15 = lane & 15, lhi = lane >> 4;
  int bx = blockIdx.x, by = blockIdx.y;
  const int m0 = by * 128, n0 = bx * 128;
  const int wm = (wave >> 1) * 64, wn = (wave & 1) * 64;
  f32x4 acc[4][4] = {};
  const int srow = wave * 32 + (lane >> 3);
  const int scolb = (lane & 7) * 16;

  for (int k0 = 0; k0 < K; k0 += 64) {
    __syncthreads();
#pragma unroll
    for (int q = 0; q < 4; ++q) {
      const int r = srow + q * 8;
      int ra = m0 + r; ra = (ra < M) ? ra : (M - 1);
      gll16((const char*)(A + (size_t)ra * K + k0) + scolb,
            (char*)As + (wave * 32 + q * 8) * 128);
      gll16((const char*)(Bm + (size_t)(n0 + r) * K + k0) + scolb,
            (char*)Bs + (wave * 32 + q * 8) * 128);
    }
    __syncthreads();
#pragma unroll
    for (int kk = 0; kk < 2; ++kk) {
      const int ko = kk * 32 + lhi * 8;
      bf16x8 af[4], bfr[4];
#pragma unroll
      for (int i = 0; i < 4; ++i) af[i] = *(const bf16x8*)(As + (wm + i * 16 + l15) * 64 + ko);
#pragma unroll
      for (int j = 0; j < 4; ++j) bfr[j] = *(const bf16x8*)(Bs + (wn + j * 16 + l15) * 64 + ko);
#pragma unroll
      for (int i = 0; i < 4; ++i)
#pragma unroll
        for (int j = 0; j < 4; ++j)
          acc[i][j] = MFMA(af[i], bfr[j], acc[i][j]);
    }
  }

#pragma unroll
  for (int i = 0; i < 4; ++i) {
    const int gr = m0 + wm + i * 16 + lhi * 4;
#pragma unroll
    for (int j = 0; j < 4; ++j) {
      const int gc = n0 + wn + j * 16 + l15;
      const float bv = bias ? bias[gc] : 0.f;
#pragma unroll
      for (int rr = 0; rr < 4; ++rr)
        ((float*)C)[(size_t)(gr + rr) * N + gc] = acc[i][j][rr] + bv;
    }
  }
}

// ---- 256^2 8-phase counted-vmcnt GEMM body (T2+T3+T4+T5), KT K-tiles.
// T2 swizzle: pre-swizzled global source column + XOR on ds_read offset.
// EPI==2: fused lse partials. EPI==4: bf16 C write. EPI==5: bf16 tanh(acc+bias).
__device__ __forceinline__ void stageHT(const u16* __restrict__ g, size_t lda,
                                        int grow0, int kcol,
                                        char* lbase, int wave, int lane) {
#pragma unroll
  for (int j = 0; j < 2; ++j) {
    const int chunk = wave * 2 + j;
    const int row = chunk * 8 + (lane >> 3);
    const int colb = ((lane & 7) ^ (lane >> 3)) << 4;   // T2 pre-swizzle
    gll16((const char*)(g + (size_t)(grow0 + row) * lda + kcol) + colb,
          lbase + chunk * 1024);
  }
}

template<int EPI, int KT>
__device__ __forceinline__ void vg_body(const u16* __restrict__ A, const u16* __restrict__ Bm,
                                        size_t lda, size_t ldb,
                                        const float* __restrict__ bias, void* __restrict__ C,
                                        int N, float* __restrict__ pmax,
                                        float* __restrict__ psum, char* LB,
                                        int bid, int nblk) {
  const int tid = threadIdx.x;
  const int wave = tid >> 6, lane = tid & 63;
  const int l15 = lane & 15, lhi = lane >> 4;
  const int wm = wave >> 2, wn = wave & 3;
  const int xr = (l15 & 7) << 4;                       // T2 read swizzle
  const int cpx = nblk >> 3;
  const int si = (bid & 7) * cpx + (bid >> 3);
  const int bx = si >> 4, by = si & 15;                // gy fixed = 16 (M=4096)
  const int m0 = by * 256, n0 = bx * 256;

  f32x4 acc[8][4] = {};
  bf16x8 br[4][2], ar[2][2];

#define ABUF(t) (LB + ((t) & 1) * 65536)
#define BBUF(t) (LB + ((t) & 1) * 65536 + 32768)
  auto stA = [&](int t, int h) {
    if (t < KT) stageHT(A, lda, m0 + h * 128, t * 64, ABUF(t) + h * 16384, wave, lane);
  };
  auto stB = [&](int t, int h) {
    if (t < KT) stageHT(Bm, ldb, n0 + h * 128, t * 64, BBUF(t) + h * 16384, wave, lane);
  };

  stA(0, 0); stA(0, 1); stB(0, 0); stB(0, 1); stB(1, 0); stB(1, 1);
  asm volatile("s_waitcnt vmcnt(4)" ::: "memory");
  __builtin_amdgcn_sched_barrier(0);
  __builtin_amdgcn_s_barrier();

  auto phase = [&](int t, int q, bool rb, int stmat, int stt, int sth) {
    const char* ab = (const char*)ABUF(t);
    const char* bb = (const char*)BBUF(t);
    if (rb) {
#pragma unroll
      for (int nf = 0; nf < 4; ++nf)
#pragma unroll
        for (int kk = 0; kk < 2; ++kk)
          br[nf][kk] = *(const bf16x8*)(bb + (wn * 64 + nf * 16 + l15) * 128 +
                                        ((kk * 64 + lhi * 16) ^ xr));
    }
#pragma unroll
    for (int m2 = 0; m2 < 2; ++m2)
#pragma unroll
      for (int kk = 0; kk < 2; ++kk)
        ar[m2][kk] = *(const bf16x8*)(ab + (wm * 128 + (q * 2 + m2) * 16 + l15) * 128 +
                                      ((kk * 64 + lhi * 16) ^ xr));
    if (stmat == 0) stA(stt, sth); else stB(stt, sth);
    __builtin_amdgcn_sched_barrier(0);
    __builtin_amdgcn_s_barrier();
    asm volatile("s_waitcnt lgkmcnt(0)" ::: "memory");
    __builtin_amdgcn_sched_barrier(0);
    __builtin_amdgcn_s_setprio(1);
#pragma unroll
    for (int m2 = 0; m2 < 2; ++m2)
#pragma unroll
      for (int nf = 0; nf < 4; ++nf)
#pragma unroll
        for (int kk = 0; kk < 2; ++kk)
          acc[q * 2 + m2][nf] = MFMA(ar[m2][kk], br[nf][kk], acc[q * 2 + m2][nf]);
    __builtin_amdgcn_s_setprio(0);
    __builtin_amdgcn_sched_barrier(0);
  };

  for (int t = 0; t < KT; t += 2) {
    phase(t, 0, true,  0, t + 1, 0);
    __builtin_amdgcn_s_barrier();
    phase(t, 1, false, 0, t + 1, 1);
    __builtin_amdgcn_s_barrier();
    phase(t, 2, false, 1, t + 2, 0);
    __builtin_amdgcn_s_barrier();
    phase(t, 3, false, 1, t + 2, 1);
    if (t == KT - 2) asm volatile("s_waitcnt vmcnt(0)" ::: "memory");
    else             asm volatile("s_waitcnt vmcnt(4)" ::: "memory");
    __builtin_amdgcn_sched_barrier(0);
    __builtin_amdgcn_s_barrier();
    phase(t + 1, 0, true,  0, t + 2, 0);
    __builtin_amdgcn_s_barrier();
    phase(t + 1, 1, false, 0, t + 2, 1);
    __builtin_amdgcn_s_barrier();
    phase(t + 1, 2, false, 1, t + 3, 0);
    __builtin_amdgcn_s_barrier();
    phase(t + 1, 3, false, 1, t + 3, 1);
    if (t == KT - 2) asm volatile("s_waitcnt vmcnt(0)" ::: "memory");
    else             asm volatile("s_waitcnt vmcnt(4)" ::: "memory");
    __builtin_amdgcn_sched_barrier(0);
    __builtin_amdgcn_s_barrier();
  }
#undef ABUF
#undef BBUF

  if (EPI == 2) {
    const int pc = bx * 4 + wn;
    float bj[4];
#pragma unroll
    for (int nf = 0; nf < 4; ++nf) bj[nf] = bias[n0 + wn * 64 + nf * 16 + l15];
#pragma unroll
    for (int mf = 0; mf < 8; ++mf) {
#pragma unroll
      for (int rr = 0; rr < 4; ++rr) {
        float v0 = acc[mf][0][rr] + bj[0];
        float v1 = acc[mf][1][rr] + bj[1];
        float v2 = acc[mf][2][rr] + bj[2];
        float v3 = acc[mf][3][rr] + bj[3];
        float m = fmaxf(fmaxf(v0, v1), fmaxf(v2, v3));
#pragma unroll
        for (int d = 1; d < 16; d <<= 1) m = fmaxf(m, __shfl_xor(m, d, 64));
        float s = __expf(v0 - m) + __expf(v1 - m) + __expf(v2 - m) + __expf(v3 - m);
#pragma unroll
        for (int d = 1; d < 16; d <<= 1) s += __shfl_xor(s, d, 64);
        if (l15 == 0) {
          const int gr = m0 + wm * 128 + mf * 16 + lhi * 4 + rr;
          pmax[(size_t)gr * 500 + pc] = m;
          psum[(size_t)gr * 500 + pc] = s;
        }
      }
    }
  } else if (EPI == 5) {
#pragma unroll
    for (int mf = 0; mf < 8; ++mf) {
      const int gr = m0 + wm * 128 + mf * 16 + lhi * 4;
#pragma unroll
      for (int nf = 0; nf < 4; ++nf) {
        const int gc = n0 + wn * 64 + nf * 16 + l15;
        const float bv = bias[gc];
#pragma unroll
        for (int rr = 0; rr < 4; ++rr)
          ((u16*)C)[(size_t)(gr + rr) * N + gc] = f2b(tanhf(acc[mf][nf][rr] + bv));
      }
    }
  } else {
#pragma unroll
    for (int mf = 0; mf < 8; ++mf) {
      const int gr = m0 + wm * 128 + mf * 16 + lhi * 4;
#pragma unroll
      for (int nf = 0; nf < 4; ++nf) {
        const int gc = n0 + wn * 64 + nf * 16 + l15;
#pragma unroll
        for (int rr = 0; rr < 4; ++rr)
          ((u16*)C)[(size_t)(gr + rr) * N + gc] = f2b(acc[mf][nf][rr]);
      }
    }
  }
}

// ---- both x-gate pre-GEMMs in ONE launch (blocks 0..255 enc, 256..511 dec) ----
__global__ __launch_bounds__(512, 2)
void k_vg_pre(const u16* __restrict__ Ae, const u16* __restrict__ Be, u16* __restrict__ Ce,
              const u16* __restrict__ Ad, const u16* __restrict__ Bd, u16* __restrict__ Cd) {
  __shared__ __align__(16) char LB[131072];
  if (blockIdx.x < 256)
    vg_body<4, 16>(Ae, Be, Hh, Hh, nullptr, Ce, NT4, nullptr, nullptr, LB, blockIdx.x, 256);
  else
    vg_body<4, 16>(Ad, Bd, Hh, Hh, nullptr, Cd, NT4, nullptr, nullptr, LB,
                   blockIdx.x - 256, 256);
}

// ---- att-GEMM: hx_att_b = bf16(tanh(Acat @ W_att^T + b_att)), 8-phase, K=2048 ----
__global__ __launch_bounds__(512, 2)
void k_attgemm(const u16* __restrict__ A, const u16* __restrict__ Bm,
               const float* __restrict__ bias, u16* __restrict__ C) {
  __shared__ __align__(16) char LB[131072];
  vg_body<5, 32>(A, Bm, 2048, 2048, bias, C, Hh, nullptr, nullptr, LB, blockIdx.x, 64);
}

// ---- vocab GEMM (8-phase 256^2 + T2) with fused lse partials ----
__global__ __launch_bounds__(512, 2)
void k_vgemm(const u16* __restrict__ A, const u16* __restrict__ Bm,
             const float* __restrict__ bias,
             float* __restrict__ pmax, float* __restrict__ psum) {
  __shared__ __align__(16) char LB[131072];
  vg_body<2, 16>(A, Bm, Hh, Hh, bias, nullptr, Vv, pmax, psum, LB, blockIdx.x, 2000);
}

// ---- persistent encoder (R8 replicated-flags scheme: best measured, 663 µs) ----
__global__ __launch_bounds__(256, 1)
void k_enc_all(const u16* __restrict__ Wb, const u16* __restrict__ gx,
               const float* __restrict__ b_ih, const float* __restrict__ b_hh,
               u16* __restrict__ hxl, float* __restrict__ c_out, int* flags) {
  __shared__ __align__(16) u16 Ws[64 * 1024];  // 128 KB, byte-XOR swizzled
  __shared__ float Gs[64 * 65];
  __shared__ float bsum[64];
  const int tid = threadIdx.x;
  const int wave = tid >> 6, lane = tid & 63;
  const int l15 = lane & 15, lhi = lane >> 4;
  const int c0 = blockIdx.x * 16;
  const int cb = tid >> 2, cq = tid & 3;
  const int rot = blockIdx.x & 31;

  for (int i = tid; i < 64 * 128; i += 256) {
    const int r = i >> 7, ck = i & 127;
    const int grow = (r >> 4) * Hh + c0 + (r & 15);
    const int bo = (ck * 16) ^ ((r & 7) << 4);
    *(bf16x8*)((char*)Ws + r * 2048 + bo) = *(const bf16x8*)(Wb + (size_t)grow * Hh + ck * 8);
  }
  if (tid < 64) {
    const int col = (tid >> 4) * Hh + c0 + (tid & 15);
    bsum[tid] = b_ih[col] + b_hh[col];
  }
  float creg[4] = {0.f, 0.f, 0.f, 0.f};
  __syncthreads();

  for (int s = 0; s < 64; ++s) {
    u64 graw[4];
#pragma unroll
    for (int g = 0; g < 4; ++g)
      graw[g] = *(const u64*)(gx + (size_t)(s * 64 + cb) * NT4 + g * Hh + c0 + cq * 4);

    f32x4 acc[4] = {};
    if (s > 0) {
      if (wave == 0) {
        for (;;) {
          const int f = AL32(flags + blockIdx.x * 64 + lane);
          if (__all(f >= s)) break;
          __builtin_amdgcn_s_sleep(1);
        }
      }
      __syncthreads();
      const u64* apw = (const u64*)(hxl + ((size_t)(s - 1) * 64 + wave * 16 + l15) * Hh);
      const char* wsb = (const char*)Ws;
      const int xr = (l15 & 7) << 4;
#pragma unroll 8
      for (int i = 0; i < 32; ++i) {
        const int kf = (i + rot) & 31;
        const int k = kf * 32 + lhi * 8;
        const u64 ua = AL(apw + (k >> 2));
        const u64 ub = AL(apw + (k >> 2) + 1);
        union { u64 qq[2]; bf16x8 v; } cv;
        cv.qq[0] = ua; cv.qq[1] = ub;
        const int kb = (k * 2) ^ xr;
#pragma unroll
        for (int nt = 0; nt < 4; ++nt)
          acc[nt] = MFMA(cv.v, *(const bf16x8*)(wsb + (nt * 16 + l15) * 2048 + kb), acc[nt]);
      }
    }
#pragma unroll
    for (int nt = 0; nt < 4; ++nt)
#pragma unroll
      for (int r = 0; r < 4; ++r)
        Gs[(wave * 16 + lhi * 4 + r) * 65 + nt * 16 + l15] = acc[nt][r];
    __syncthreads();
    {
      const float* gsrow = Gs + cb * 65;
      u64 pk = 0;
#pragma unroll
      for (int j = 0; j < 4; ++j) {
        const int col = cq * 4 + j;
        const float gi = gsrow[col]      + b2f((u16)(graw[0] >> (16 * j))) + bsum[col];
        const float gf = gsrow[16 + col] + b2f((u16)(graw[1] >> (16 * j))) + bsum[16 + col];
        const float gg = gsrow[32 + col] + b2f((u16)(graw[2] >> (16 * j))) + bsum[32 + col];
        const float go = gsrow[48 + col] + b2f((u16)(graw[3] >> (16 * j))) + bsum[48 + col];
        const float cn = sigf(gf) * creg[j] + sigf(gi) * tanhf(gg);
        const float hv = sigf(go) * tanhf(cn);
        creg[j] = cn;
        pk |= (u64)f2b(hv) << (16 * j);
      }
      AS((u64*)(hxl + ((size_t)s * 64 + cb) * Hh + c0 + cq * 4), pk);
    }
    __syncthreads();
    if (tid < ENC_NBLK)
      AS32(flags + tid * 64 + blockIdx.x, s + 1);
  }
#pragma unroll
  for (int j = 0; j < 4; ++j)
    c_out[cb * Hh + c0 + cq * 4 + j] = creg[j];
}

// ---- fused decoder-cell + attention per (t,b), XCD-affinity remap:
// all 63 t-blocks of a given b land on one XCD (assuming round-robin
// dispatch) -> that b's 128 KB hxl column stays L2-resident. ----
__global__ __launch_bounds__(256)
void k_dattn(u16* __restrict__ Acat, const u16* __restrict__ hxl,
             const int* __restrict__ src, const u16* __restrict__ G,
             const float* __restrict__ dbase, const float* __restrict__ cT,
             const float* __restrict__ b_ih, const float* __restrict__ b_hh) {
  __shared__ float qs[Hh];
  __shared__ float sc[Ss];
  // bid -> (b, t): xcd = bid&7; b = xcd + 8*((bid>>3)&7); t = bid>>6  (bijective)
  const int bid = blockIdx.x;
  const int b = (bid & 7) + 8 * ((bid >> 3) & 7);
  const int t = bid >> 6;
  const int r = t * 64 + b;
  const int tid = threadIdx.x, wave = tid >> 6, lane = tid & 63;
  {  // decoder cell for this row (4 cols per thread)
    const int c4 = tid * 4;
    u64 graw[4]; f32x4 dv[4], bi[4], bh[4];
#pragma unroll
    for (int g = 0; g < 4; ++g) {
      graw[g] = *(const u64*)(G + (size_t)r * NT4 + g * Hh + c4);
      dv[g] = *(const f32x4*)(dbase + (size_t)b * NT4 + g * Hh + c4);
      bi[g] = *(const f32x4*)(b_ih + g * Hh + c4);
      bh[g] = *(const f32x4*)(b_hh + g * Hh + c4);
    }
    const f32x4 cv4 = *(const f32x4*)(cT + b * Hh + c4);
    u64 pk = 0;
#pragma unroll
    for (int j = 0; j < 4; ++j) {
      const float gi = b2f((u16)(graw[0] >> (16 * j))) + dv[0][j] + bi[0][j] + bh[0][j];
      const float gf = b2f((u16)(graw[1] >> (16 * j))) + dv[1][j] + bi[1][j] + bh[1][j];
      const float gg = b2f((u16)(graw[2] >> (16 * j))) + dv[2][j] + bi[2][j] + bh[2][j];
      const float go = b2f((u16)(graw[3] >> (16 * j))) + dv[3][j] + bi[3][j] + bh[3][j];
      const float cn = sigf(gf) * cv4[j] + sigf(gi) * tanhf(gg);
      const float hv = sigf(go) * tanhf(cn);
      qs[c4 + j] = hv;
      pk |= (u64)f2b(hv) << (16 * j);
    }
    *(u64*)(Acat + (size_t)r * 2048 + Hh + c4) = pk;
  }
  __syncthreads();
  for (int sub = 0; sub < 16; ++sub) {
    const int ss = wave * 16 + sub;
    const ushort4* hp4 = (const ushort4*)(hxl + ((size_t)ss * Bb + b) * Hh);
    float p = 0.f;
#pragma unroll
    for (int q = 0; q < 4; ++q) {
      const int i4 = lane + 64 * q;
      const ushort4 v = hp4[i4];
      p += qs[i4 * 4 + 0] * b2f(v.x) + qs[i4 * 4 + 1] * b2f(v.y)
         + qs[i4 * 4 + 2] * b2f(v.z) + qs[i4 * 4 + 3] * b2f(v.w);
    }
#pragma unroll
    for (int d = 1; d < 64; d <<= 1) p += __shfl_xor(p, d, 64);
    if (lane == 0) sc[ss] = (src[b * 64 + ss] != 0) ? p : -INFINITY;
  }
  __syncthreads();
  if (wave == 0) {
    const float v = sc[lane];
    float m = v;
#pragma unroll
    for (int d = 1; d < 64; d <<= 1) m = fmaxf(m, __shfl_xor(m, d, 64));
    const float e = __expf(v - m);
    float ssum = e;
#pragma unroll
    for (int d = 1; d < 64; d <<= 1) ssum += __shfl_xor(ssum, d, 64);
    sc[lane] = e / ssum;
  }
  __syncthreads();
  float4 a4 = {0.f, 0.f, 0.f, 0.f};
  for (int s2 = 0; s2 < 64; ++s2) {
    const float a = sc[s2];
    const ushort4 v = *(const ushort4*)(hxl + ((size_t)s2 * Bb + b) * Hh + tid * 4);
    a4.x += a * b2f(v.x); a4.y += a * b2f(v.y);
    a4.z += a * b2f(v.z); a4.w += a * b2f(v.w);
  }
  u16* dst = Acat + (size_t)r * 2048 + tid * 4;
  dst[0] = f2b(a4.x); dst[1] = f2b(a4.y); dst[2] = f2b(a4.z); dst[3] = f2b(a4.w);
}

// ---- merged: lse combine + target logit -> nll[r] ----
__global__ void k_lsetl(const float* __restrict__ pmax, const float* __restrict__ psum,
                        const u16* __restrict__ hx_att_b, const int* __restrict__ target,
                        const float* __restrict__ W, const float* __restrict__ bo,
                        float* __restrict__ nll, int ncols) {
  const int r = blockIdx.x * 4 + (threadIdx.x >> 6);
  const int lane = threadIdx.x & 63;
  if (r >= RD) return;
  float m = -INFINITY;
  for (int i = lane; i < ncols; i += 64) m = fmaxf(m, pmax[(size_t)r * ncols + i]);
#pragma unroll
  for (int d = 1; d < 64; d <<= 1) m = fmaxf(m, __shfl_xor(m, d, 64));
  float s = 0.f;
  for (int i = lane; i < ncols; i += 64)
    s += psum[(size_t)r * ncols + i] * __expf(pmax[(size_t)r * ncols + i] - m);
#pragma unroll
  for (int d = 1; d < 64; d <<= 1) s += __shfl_xor(s, d, 64);
  const int t = r >> 6, b = r & 63;
  const int w = target[b * 64 + t + 1];
  const u16* a = hx_att_b + (size_t)r * Hh;
  const float* wr = W + (size_t)w * Hh;
  float p = 0.f;
  for (int h = lane; h < Hh; h += 64) p += b2f(a[h]) * wr[h];
#pragma unroll
  for (int d = 1; d < 64; d <<= 1) p += __shfl_xor(p, d, 64);
  if (lane == 0) nll[r] = (m + logf(s)) - (p + bo[w]);
}

// ---- final reduction -> scalar loss
__global__ void k_final(const float* __restrict__ nll, const int* __restrict__ target,
                        float* __restrict__ out) {
  const int t = threadIdx.x;
  float ps = 0.f;
  if (t < 63) {
    float sn = 0.f, cnt = 0.f;
    for (int b = 0; b < 64; ++b) {
      const int r = t * 64 + b;
      const int w = target[b * 64 + t + 1];
      if (w != 0) { sn += nll[r]; cnt += 1.f; }
    }
    ps = sn / fmaxf(cnt, 1.f);
  }
#pragma unroll
  for (int d = 1; d < 64; d <<= 1) ps += __shfl_xor(ps, d, 64);
  if (t == 0) out[0] = ps;
}

extern "C" void kernel_launch(void* const* d_in, const int* in_sizes, int n_in,
                              void* d_out, int out_size, void* d_ws, size_t ws_size,
                              hipStream_t stream) {
  const int*   source   = (const int*)d_in[0];
  const int*   target   = (const int*)d_in[1];
  const float* emb_src  = (const float*)d_in[2];
  const float* emb_tgt  = (const float*)d_in[3];
  const float* W_ih_enc = (const float*)d_in[4];
  const float* W_hh_enc = (const float*)d_in[5];
  const float* b_ih_enc = (const float*)d_in[6];
  const float* b_hh_enc = (const float*)d_in[7];
  const float* W_ih_dec = (const float*)d_in[8];
  const float* W_hh_dec = (const float*)d_in[9];
  const float* b_ih_dec = (const float*)d_in[10];
  const float* b_hh_dec = (const float*)d_in[11];
  const float* W_att    = (const float*)d_in[12];
  const float* b_att    = (const float*)d_in[13];
  const float* W_out    = (const float*)d_in[14];
  const float* b_out    = (const float*)d_in[15];
  float* out = (float*)d_out;

  char* base = (char*)d_ws;
  size_t off = 0;
  auto alloc = [&](size_t bytes) -> void* {
    void* r = base + off; off += (bytes + 255) & ~(size_t)255; return r;
  };
  u16*   wb_ih_enc = (u16*)alloc((size_t)NT4 * Hh * 2);
  u16*   wb_hh_enc = (u16*)alloc((size_t)NT4 * Hh * 2);
  u16*   wb_ih_dec = (u16*)alloc((size_t)NT4 * Hh * 2);
  u16*   wb_hh_dec = (u16*)alloc((size_t)NT4 * Hh * 2);
  u16*   wb_att    = (u16*)alloc((size_t)Hh * 2048 * 2);
  u16*   wb_out    = (u16*)alloc((size_t)Vv * Hh * 2);
  u16*   x_src_b   = (u16*)alloc((size_t)RP * Hh * 2);
  u16*   x_dec_b   = (u16*)alloc((size_t)RP * Hh * 2);
  u16*   gates16   = (u16*)alloc((size_t)RP * NT4 * 2);
  u16*   gates_dec = (u16*)alloc((size_t)RP * NT4 * 2);
  u16*   hxl       = (u16*)alloc((size_t)Ss * Bb * Hh * 2);
  float* c_enc     = (float*)alloc((size_t)Bb * Hh * 4);
  float* dbase     = (float*)alloc((size_t)128 * NT4 * 4);
  u16*   Acat      = (u16*)alloc((size_t)RP * 2048 * 2);
  u16*   hx_att_b  = (u16*)alloc((size_t)RP * Hh * 2);
  float* pmax      = (float*)alloc((size_t)RP * 500 * 4);
  float* psum      = (float*)alloc((size_t)RP * 500 * 4);
  float* nll       = (float*)alloc((size_t)RD * 4);
  int*   flags     = (int*)alloc(ENC_NBLK * ENC_NBLK * 4);

  if (off > ws_size) { k_fail<<<1, 1, 0, stream>>>(out); return; }

  // weights -> bf16 + both embedding gathers (one launch)
  k_prep<<<2048 + 2 * RP, 256, 0, stream>>>(W_ih_enc, wb_ih_enc, W_hh_enc, wb_hh_enc,
                                            W_ih_dec, wb_ih_dec, W_hh_dec, wb_hh_dec,
                                            W_att, wb_att, W_out, wb_out,
                                            source, emb_src, x_src_b,
                                            target, emb_tgt, x_dec_b);

  hipMemsetAsync(flags, 0, ENC_NBLK * ENC_NBLK * 4, stream);

  // enc + dec x-gate pre-GEMMs (one launch, 8-phase 256^2)
  k_vg_pre<<<512, 512, 0, stream>>>(x_src_b, wb_ih_enc, gates16,
                                    x_dec_b, wb_ih_dec, gates_dec);

  // persistent dataflow encoder (R8 flags scheme)
  k_enc_all<<<ENC_NBLK, 256, 0, stream>>>(wb_hh_enc, gates16, b_ih_enc, b_hh_enc,
                                          hxl, c_enc, flags);

  // hT base
  k_gemm<0><<<dim3(32, 1), 256, 0, stream>>>(hxl + (size_t)63 * Bb * Hh, wb_hh_dec, dbase,
                                             64, NT4, Hh, nullptr);

  // fused decoder cell + attention -> Acat[:,H..] and Acat[:, :H]
  k_dattn<<<RD, 256, 0, stream>>>(Acat, hxl, source, gates_dec, dbase, c_enc,
                                  b_ih_dec, b_hh_dec);

  // hx_att_b = bf16(tanh(A_cat @ W_att^T + b_att)) on 8-phase template (K=2048)
  k_attgemm<<<64, 512, 0, stream>>>(Acat, wb_att, b_att, hx_att_b);

  // vocab GEMM (8-phase 256^2 + T2 swizzle) with fused lse partials
  k_vgemm<<<2000, 512, 0, stream>>>(hx_att_b, wb_out, b_out, pmax, psum);
  k_lsetl<<<(RD + 3) / 4, 256, 0, stream>>>(pmax, psum, hx_att_b, target, W_out, b_out,
                                            nll, 500);
  k_final<<<1, 64, 0, stream>>>(nll, target, out);
}

// Round 16
// 1281.841 us; speedup vs baseline: 1.0024x; 1.0024x over previous
//
#include <hip/hip_runtime.h>
#include <math.h>

#define Bb 64
#define Ss 64
#define Hh 1024
#define Vv 32000
#define RD 4032     // 63*64 decoder rows
#define RP 4096     // padded rows
#define NT4 4096    // 4*H
#define ENC_NBLK 64

typedef unsigned short u16;
typedef unsigned long long u64;
typedef __attribute__((ext_vector_type(8))) short bf16x8;
typedef __attribute__((ext_vector_type(4))) float f32x4;

#define MFMA(a, b, c) __builtin_amdgcn_mfma_f32_16x16x32_bf16(a, b, c, 0, 0, 0)

__device__ __forceinline__ u16 f2b(float f) {
  union { float f; unsigned u; } v; v.f = f;
  unsigned r = v.u + 0x7fffu + ((v.u >> 16) & 1u);
  return (u16)(r >> 16);
}
__device__ __forceinline__ float b2f(u16 b) {
  union { unsigned u; float f; } v; v.u = ((unsigned)b) << 16; return v.f;
}
__device__ __forceinline__ float sigf(float x) { return 1.f / (1.f + expf(-x)); }

__device__ __forceinline__ u64 AL(const u64* p) {
  return __hip_atomic_load(p, __ATOMIC_RELAXED, __HIP_MEMORY_SCOPE_AGENT);
}
__device__ __forceinline__ void AS(u64* p, u64 v) {
  __hip_atomic_store(p, v, __ATOMIC_RELAXED, __HIP_MEMORY_SCOPE_AGENT);
}
__device__ __forceinline__ int AL32(const int* p) {
  return __hip_atomic_load(p, __ATOMIC_RELAXED, __HIP_MEMORY_SCOPE_AGENT);
}
__device__ __forceinline__ void AS32(int* p, int v) {
  __hip_atomic_store(p, v, __ATOMIC_RELAXED, __HIP_MEMORY_SCOPE_AGENT);
}

__device__ __forceinline__ void gll16(const void* g, void* l) {
  __builtin_amdgcn_global_load_lds(
      (const __attribute__((address_space(1))) unsigned int*)g,
      (__attribute__((address_space(3))) unsigned int*)l, 16, 0, 0);
}

__global__ void k_fail(float* out) { out[0] = 1e30f; }

// ---- merged prep: weights f32->bf16 (blocks 0..2047, grid-stride) +
// both embedding gathers (blocks 2048..10239) + flags zero (block 10240) ----
__global__ void k_prep(const float* __restrict__ s0, u16* __restrict__ d0,
                       const float* __restrict__ s1, u16* __restrict__ d1,
                       const float* __restrict__ s2, u16* __restrict__ d2,
                       const float* __restrict__ s3, u16* __restrict__ d3,
                       const float* __restrict__ s4, u16* __restrict__ d4,
                       const float* __restrict__ s5, u16* __restrict__ d5,
                       const int* __restrict__ src_tok, const float* __restrict__ emb_s,
                       u16* __restrict__ out_s,
                       const int* __restrict__ tgt_tok, const float* __restrict__ emb_t,
                       u16* __restrict__ out_t, int* __restrict__ flags) {
  if (blockIdx.x == 2048 + 2 * RP) {
    for (int i = threadIdx.x; i < ENC_NBLK * ENC_NBLK; i += 256) flags[i] = 0;
    return;
  }
  if (blockIdx.x < 2048) {
    const int A4 = NT4 * Hh / 4;
    const int E4 = Hh * 2048 / 4;
    const int F4 = Vv * Hh / 4;
    const int TOT = 4 * A4 + E4 + F4;
    const int st = 2048 * 256;
    for (int i = blockIdx.x * 256 + threadIdx.x; i < TOT; i += st) {
      const float* sp; u16* dp; int off;
      if (i < A4)            { sp = s0; dp = d0; off = i; }
      else if (i < 2 * A4)   { sp = s1; dp = d1; off = i - A4; }
      else if (i < 3 * A4)   { sp = s2; dp = d2; off = i - 2 * A4; }
      else if (i < 4 * A4)   { sp = s3; dp = d3; off = i - 3 * A4; }
      else if (i < 4 * A4 + E4) { sp = s4; dp = d4; off = i - 4 * A4; }
      else                   { sp = s5; dp = d5; off = i - 4 * A4 - E4; }
      const float4 v = ((const float4*)sp)[off];
      ushort4 o; o.x = f2b(v.x); o.y = f2b(v.y); o.z = f2b(v.z); o.w = f2b(v.w);
      ((ushort4*)dp)[off] = o;
    }
  } else {
    int r = blockIdx.x - 2048;
    const int* tok; const float* emb; u16* outp; int nstep;
    if (r < RP) { tok = src_tok; emb = emb_s; outp = out_s; nstep = 64; }
    else        { r -= RP; tok = tgt_tok; emb = emb_t; outp = out_t; nstep = 63; }
    const int step = r >> 6, b = r & 63;
    const int idx = (step < nstep) ? tok[b * 64 + step] : 0;
    const float4 v = ((const float4*)(emb + (size_t)idx * Hh))[threadIdx.x];
    ushort4 o; o.x = f2b(v.x); o.y = f2b(v.y); o.z = f2b(v.z); o.w = f2b(v.w);
    ((ushort4*)(outp + (size_t)r * Hh))[threadIdx.x] = o;
  }
}

// ---- 256^2 8-phase counted-vmcnt GEMM body (T2+T3+T4+T5), KT K-tiles.
// T2 swizzle: pre-swizzled global source column + XOR on ds_read offset.
// EPI==2: fused lse partials. EPI==4: bf16 C write. EPI==5: bf16 tanh(acc+bias).
__device__ __forceinline__ void stageHT(const u16* __restrict__ g, size_t lda,
                                        int grow0, int kcol,
                                        char* lbase, int wave, int lane) {
#pragma unroll
  for (int j = 0; j < 2; ++j) {
    const int chunk = wave * 2 + j;
    const int row = chunk * 8 + (lane >> 3);
    const int colb = ((lane & 7) ^ (lane >> 3)) << 4;   // T2 pre-swizzle
    gll16((const char*)(g + (size_t)(grow0 + row) * lda + kcol) + colb,
          lbase + chunk * 1024);
  }
}

template<int EPI, int KT>
__device__ __forceinline__ void vg_body(const u16* __restrict__ A, const u16* __restrict__ Bm,
                                        size_t lda, size_t ldb,
                                        const float* __restrict__ bias, void* __restrict__ C,
                                        int N, float* __restrict__ pmax,
                                        float* __restrict__ psum, char* LB,
                                        int bid, int nblk) {
  const int tid = threadIdx.x;
  const int wave = tid >> 6, lane = tid & 63;
  const int l15 = lane & 15, lhi = lane >> 4;
  const int wm = wave >> 2, wn = wave & 3;
  const int xr = (l15 & 7) << 4;                       // T2 read swizzle
  const int cpx = nblk >> 3;
  const int si = (bid & 7) * cpx + (bid >> 3);
  const int bx = si >> 4, by = si & 15;                // gy fixed = 16 (M=4096)
  const int m0 = by * 256, n0 = bx * 256;

  f32x4 acc[8][4] = {};
  bf16x8 br[4][2], ar[2][2];

#define ABUF(t) (LB + ((t) & 1) * 65536)
#define BBUF(t) (LB + ((t) & 1) * 65536 + 32768)
  auto stA = [&](int t, int h) {
    if (t < KT) stageHT(A, lda, m0 + h * 128, t * 64, ABUF(t) + h * 16384, wave, lane);
  };
  auto stB = [&](int t, int h) {
    if (t < KT) stageHT(Bm, ldb, n0 + h * 128, t * 64, BBUF(t) + h * 16384, wave, lane);
  };

  stA(0, 0); stA(0, 1); stB(0, 0); stB(0, 1); stB(1, 0); stB(1, 1);
  asm volatile("s_waitcnt vmcnt(4)" ::: "memory");
  __builtin_amdgcn_sched_barrier(0);
  __builtin_amdgcn_s_barrier();

  auto phase = [&](int t, int q, bool rb, int stmat, int stt, int sth) {
    const char* ab = (const char*)ABUF(t);
    const char* bb = (const char*)BBUF(t);
    if (rb) {
#pragma unroll
      for (int nf = 0; nf < 4; ++nf)
#pragma unroll
        for (int kk = 0; kk < 2; ++kk)
          br[nf][kk] = *(const bf16x8*)(bb + (wn * 64 + nf * 16 + l15) * 128 +
                                        ((kk * 64 + lhi * 16) ^ xr));
    }
#pragma unroll
    for (int m2 = 0; m2 < 2; ++m2)
#pragma unroll
      for (int kk = 0; kk < 2; ++kk)
        ar[m2][kk] = *(const bf16x8*)(ab + (wm * 128 + (q * 2 + m2) * 16 + l15) * 128 +
                                      ((kk * 64 + lhi * 16) ^ xr));
    if (stmat == 0) stA(stt, sth); else stB(stt, sth);
    __builtin_amdgcn_sched_barrier(0);
    __builtin_amdgcn_s_barrier();
    asm volatile("s_waitcnt lgkmcnt(0)" ::: "memory");
    __builtin_amdgcn_sched_barrier(0);
    __builtin_amdgcn_s_setprio(1);
#pragma unroll
    for (int m2 = 0; m2 < 2; ++m2)
#pragma unroll
      for (int nf = 0; nf < 4; ++nf)
#pragma unroll
        for (int kk = 0; kk < 2; ++kk)
          acc[q * 2 + m2][nf] = MFMA(ar[m2][kk], br[nf][kk], acc[q * 2 + m2][nf]);
    __builtin_amdgcn_s_setprio(0);
    __builtin_amdgcn_sched_barrier(0);
  };

  for (int t = 0; t < KT; t += 2) {
    phase(t, 0, true,  0, t + 1, 0);
    __builtin_amdgcn_s_barrier();
    phase(t, 1, false, 0, t + 1, 1);
    __builtin_amdgcn_s_barrier();
    phase(t, 2, false, 1, t + 2, 0);
    __builtin_amdgcn_s_barrier();
    phase(t, 3, false, 1, t + 2, 1);
    if (t == KT - 2) asm volatile("s_waitcnt vmcnt(0)" ::: "memory");
    else             asm volatile("s_waitcnt vmcnt(4)" ::: "memory");
    __builtin_amdgcn_sched_barrier(0);
    __builtin_amdgcn_s_barrier();
    phase(t + 1, 0, true,  0, t + 2, 0);
    __builtin_amdgcn_s_barrier();
    phase(t + 1, 1, false, 0, t + 2, 1);
    __builtin_amdgcn_s_barrier();
    phase(t + 1, 2, false, 1, t + 3, 0);
    __builtin_amdgcn_s_barrier();
    phase(t + 1, 3, false, 1, t + 3, 1);
    if (t == KT - 2) asm volatile("s_waitcnt vmcnt(0)" ::: "memory");
    else             asm volatile("s_waitcnt vmcnt(4)" ::: "memory");
    __builtin_amdgcn_sched_barrier(0);
    __builtin_amdgcn_s_barrier();
  }
#undef ABUF
#undef BBUF

  if (EPI == 2) {
    const int pc = bx * 4 + wn;
    float bj[4];
#pragma unroll
    for (int nf = 0; nf < 4; ++nf) bj[nf] = bias[n0 + wn * 64 + nf * 16 + l15];
#pragma unroll
    for (int mf = 0; mf < 8; ++mf) {
#pragma unroll
      for (int rr = 0; rr < 4; ++rr) {
        float v0 = acc[mf][0][rr] + bj[0];
        float v1 = acc[mf][1][rr] + bj[1];
        float v2 = acc[mf][2][rr] + bj[2];
        float v3 = acc[mf][3][rr] + bj[3];
        float m = fmaxf(fmaxf(v0, v1), fmaxf(v2, v3));
#pragma unroll
        for (int d = 1; d < 16; d <<= 1) m = fmaxf(m, __shfl_xor(m, d, 64));
        float s = __expf(v0 - m) + __expf(v1 - m) + __expf(v2 - m) + __expf(v3 - m);
#pragma unroll
        for (int d = 1; d < 16; d <<= 1) s += __shfl_xor(s, d, 64);
        if (l15 == 0) {
          const int gr = m0 + wm * 128 + mf * 16 + lhi * 4 + rr;
          pmax[(size_t)gr * 500 + pc] = m;
          psum[(size_t)gr * 500 + pc] = s;
        }
      }
    }
  } else if (EPI == 5) {
#pragma unroll
    for (int mf = 0; mf < 8; ++mf) {
      const int gr = m0 + wm * 128 + mf * 16 + lhi * 4;
#pragma unroll
      for (int nf = 0; nf < 4; ++nf) {
        const int gc = n0 + wn * 64 + nf * 16 + l15;
        const float bv = bias[gc];
#pragma unroll
        for (int rr = 0; rr < 4; ++rr)
          ((u16*)C)[(size_t)(gr + rr) * N + gc] = f2b(tanhf(acc[mf][nf][rr] + bv));
      }
    }
  } else {
#pragma unroll
    for (int mf = 0; mf < 8; ++mf) {
      const int gr = m0 + wm * 128 + mf * 16 + lhi * 4;
#pragma unroll
      for (int nf = 0; nf < 4; ++nf) {
        const int gc = n0 + wn * 64 + nf * 16 + l15;
#pragma unroll
        for (int rr = 0; rr < 4; ++rr)
          ((u16*)C)[(size_t)(gr + rr) * N + gc] = f2b(acc[mf][nf][rr]);
      }
    }
  }
}

// ---- both x-gate pre-GEMMs in ONE launch (blocks 0..255 enc, 256..511 dec) ----
__global__ __launch_bounds__(512, 2)
void k_vg_pre(const u16* __restrict__ Ae, const u16* __restrict__ Be, u16* __restrict__ Ce,
              const u16* __restrict__ Ad, const u16* __restrict__ Bd, u16* __restrict__ Cd) {
  __shared__ __align__(16) char LB[131072];
  if (blockIdx.x < 256)
    vg_body<4, 16>(Ae, Be, Hh, Hh, nullptr, Ce, NT4, nullptr, nullptr, LB, blockIdx.x, 256);
  else
    vg_body<4, 16>(Ad, Bd, Hh, Hh, nullptr, Cd, NT4, nullptr, nullptr, LB,
                   blockIdx.x - 256, 256);
}

// ---- att-GEMM: hx_att_b = bf16(tanh(Acat @ W_att^T + b_att)), 8-phase, K=2048 ----
__global__ __launch_bounds__(512, 2)
void k_attgemm(const u16* __restrict__ A, const u16* __restrict__ Bm,
               const float* __restrict__ bias, u16* __restrict__ C) {
  __shared__ __align__(16) char LB[131072];
  vg_body<5, 32>(A, Bm, 2048, 2048, bias, C, Hh, nullptr, nullptr, LB, blockIdx.x, 64);
}

// ---- vocab GEMM (8-phase 256^2 + T2) with fused lse partials ----
__global__ __launch_bounds__(512, 2)
void k_vgemm(const u16* __restrict__ A, const u16* __restrict__ Bm,
             const float* __restrict__ bias,
             float* __restrict__ pmax, float* __restrict__ psum) {
  __shared__ __align__(16) char LB[131072];
  vg_body<2, 16>(A, Bm, Hh, Hh, bias, nullptr, Vv, pmax, psum, LB, blockIdx.x, 2000);
}

// ---- persistent encoder (R8 replicated-flags scheme) + fused dbase epilogue:
// after the final flag-wait (flags>=64), each block runs one handshake-free
// step-shaped MFMA pass with B-frags read directly from W_hh_dec global
// (row nt*Hh+c0+l15 — identical mapping to the in-loop LDS layout) and
// writes its 4-gate x 16-col slice of dbase (fp32, no bias). ----
__global__ __launch_bounds__(256, 1)
void k_enc_all(const u16* __restrict__ Wb, const u16* __restrict__ gx,
               const float* __restrict__ b_ih, const float* __restrict__ b_hh,
               u16* __restrict__ hxl, float* __restrict__ c_out, int* flags,
               const u16* __restrict__ Wdec, float* __restrict__ dbase) {
  __shared__ __align__(16) u16 Ws[64 * 1024];  // 128 KB, byte-XOR swizzled
  __shared__ float Gs[64 * 65];
  __shared__ float bsum[64];
  const int tid = threadIdx.x;
  const int wave = tid >> 6, lane = tid & 63;
  const int l15 = lane & 15, lhi = lane >> 4;
  const int c0 = blockIdx.x * 16;
  const int cb = tid >> 2, cq = tid & 3;
  const int rot = blockIdx.x & 31;

  for (int i = tid; i < 64 * 128; i += 256) {
    const int r = i >> 7, ck = i & 127;
    const int grow = (r >> 4) * Hh + c0 + (r & 15);
    const int bo = (ck * 16) ^ ((r & 7) << 4);
    *(bf16x8*)((char*)Ws + r * 2048 + bo) = *(const bf16x8*)(Wb + (size_t)grow * Hh + ck * 8);
  }
  if (tid < 64) {
    const int col = (tid >> 4) * Hh + c0 + (tid & 15);
    bsum[tid] = b_ih[col] + b_hh[col];
  }
  float creg[4] = {0.f, 0.f, 0.f, 0.f};
  __syncthreads();

  for (int s = 0; s < 64; ++s) {
    u64 graw[4];
#pragma unroll
    for (int g = 0; g < 4; ++g)
      graw[g] = *(const u64*)(gx + (size_t)(s * 64 + cb) * NT4 + g * Hh + c0 + cq * 4);

    f32x4 acc[4] = {};
    if (s > 0) {
      if (wave == 0) {
        for (;;) {
          const int f = AL32(flags + blockIdx.x * 64 + lane);
          if (__all(f >= s)) break;
          __builtin_amdgcn_s_sleep(1);
        }
      }
      __syncthreads();
      const u64* apw = (const u64*)(hxl + ((size_t)(s - 1) * 64 + wave * 16 + l15) * Hh);
      const char* wsb = (const char*)Ws;
      const int xr = (l15 & 7) << 4;
#pragma unroll 8
      for (int i = 0; i < 32; ++i) {
        const int kf = (i + rot) & 31;
        const int k = kf * 32 + lhi * 8;
        const u64 ua = AL(apw + (k >> 2));
        const u64 ub = AL(apw + (k >> 2) + 1);
        union { u64 qq[2]; bf16x8 v; } cv;
        cv.qq[0] = ua; cv.qq[1] = ub;
        const int kb = (k * 2) ^ xr;
#pragma unroll
        for (int nt = 0; nt < 4; ++nt)
          acc[nt] = MFMA(cv.v, *(const bf16x8*)(wsb + (nt * 16 + l15) * 2048 + kb), acc[nt]);
      }
    }
#pragma unroll
    for (int nt = 0; nt < 4; ++nt)
#pragma unroll
      for (int r = 0; r < 4; ++r)
        Gs[(wave * 16 + lhi * 4 + r) * 65 + nt * 16 + l15] = acc[nt][r];
    __syncthreads();
    {
      const float* gsrow = Gs + cb * 65;
      u64 pk = 0;
#pragma unroll
      for (int j = 0; j < 4; ++j) {
        const int col = cq * 4 + j;
        const float gi = gsrow[col]      + b2f((u16)(graw[0] >> (16 * j))) + bsum[col];
        const float gf = gsrow[16 + col] + b2f((u16)(graw[1] >> (16 * j))) + bsum[16 + col];
        const float gg = gsrow[32 + col] + b2f((u16)(graw[2] >> (16 * j))) + bsum[32 + col];
        const float go = gsrow[48 + col] + b2f((u16)(graw[3] >> (16 * j))) + bsum[48 + col];
        const float cn = sigf(gf) * creg[j] + sigf(gi) * tanhf(gg);
        const float hv = sigf(go) * tanhf(cn);
        creg[j] = cn;
        pk |= (u64)f2b(hv) << (16 * j);
      }
      AS((u64*)(hxl + ((size_t)s * 64 + cb) * Hh + c0 + cq * 4), pk);
    }
    __syncthreads();
    if (tid < ENC_NBLK)
      AS32(flags + tid * 64 + blockIdx.x, s + 1);
  }

  // ---- epilogue: dbase = hT @ W_hh_dec^T (this block's 64 gate-rows) ----
  if (wave == 0) {
    for (;;) {
      const int f = AL32(flags + blockIdx.x * 64 + lane);
      if (__all(f >= 64)) break;
      __builtin_amdgcn_s_sleep(1);
    }
  }
  __syncthreads();
  {
    f32x4 acc[4] = {};
    const u64* apw = (const u64*)(hxl + ((size_t)63 * 64 + wave * 16 + l15) * Hh);
#pragma unroll 4
    for (int kf = 0; kf < 32; ++kf) {
      const int k = kf * 32 + lhi * 8;
      const u64 ua = AL(apw + (k >> 2));
      const u64 ub = AL(apw + (k >> 2) + 1);
      union { u64 qq[2]; bf16x8 v; } cv;
      cv.qq[0] = ua; cv.qq[1] = ub;
#pragma unroll
      for (int nt = 0; nt < 4; ++nt) {
        const bf16x8 bf = *(const bf16x8*)(Wdec + (size_t)(nt * Hh + c0 + l15) * Hh + k);
        acc[nt] = MFMA(cv.v, bf, acc[nt]);
      }
    }
#pragma unroll
    for (int nt = 0; nt < 4; ++nt)
#pragma unroll
      for (int r2 = 0; r2 < 4; ++r2)
        Gs[(wave * 16 + lhi * 4 + r2) * 65 + nt * 16 + l15] = acc[nt][r2];
    __syncthreads();
#pragma unroll
    for (int g = 0; g < 4; ++g) {
      f32x4 v;
#pragma unroll
      for (int j = 0; j < 4; ++j) v[j] = Gs[cb * 65 + g * 16 + cq * 4 + j];
      *(f32x4*)(dbase + (size_t)cb * NT4 + g * Hh + c0 + cq * 4) = v;
    }
  }
#pragma unroll
  for (int j = 0; j < 4; ++j)
    c_out[cb * Hh + c0 + cq * 4 + j] = creg[j];
}

// ---- fused decoder-cell + attention per (t,b), XCD-affinity remap ----
__global__ __launch_bounds__(256)
void k_dattn(u16* __restrict__ Acat, const u16* __restrict__ hxl,
             const int* __restrict__ src, const u16* __restrict__ G,
             const float* __restrict__ dbase, const float* __restrict__ cT,
             const float* __restrict__ b_ih, const float* __restrict__ b_hh) {
  __shared__ float qs[Hh];
  __shared__ float sc[Ss];
  const int bid = blockIdx.x;
  const int b = (bid & 7) + 8 * ((bid >> 3) & 7);
  const int t = bid >> 6;
  const int r = t * 64 + b;
  const int tid = threadIdx.x, wave = tid >> 6, lane = tid & 63;
  {  // decoder cell for this row (4 cols per thread)
    const int c4 = tid * 4;
    u64 graw[4]; f32x4 dv[4], bi[4], bh[4];
#pragma unroll
    for (int g = 0; g < 4; ++g) {
      graw[g] = *(const u64*)(G + (size_t)r * NT4 + g * Hh + c4);
      dv[g] = *(const f32x4*)(dbase + (size_t)b * NT4 + g * Hh + c4);
      bi[g] = *(const f32x4*)(b_ih + g * Hh + c4);
      bh[g] = *(const f32x4*)(b_hh + g * Hh + c4);
    }
    const f32x4 cv4 = *(const f32x4*)(cT + b * Hh + c4);
    u64 pk = 0;
#pragma unroll
    for (int j = 0; j < 4; ++j) {
      const float gi = b2f((u16)(graw[0] >> (16 * j))) + dv[0][j] + bi[0][j] + bh[0][j];
      const float gf = b2f((u16)(graw[1] >> (16 * j))) + dv[1][j] + bi[1][j] + bh[1][j];
      const float gg = b2f((u16)(graw[2] >> (16 * j))) + dv[2][j] + bi[2][j] + bh[2][j];
      const float go = b2f((u16)(graw[3] >> (16 * j))) + dv[3][j] + bi[3][j] + bh[3][j];
      const float cn = sigf(gf) * cv4[j] + sigf(gi) * tanhf(gg);
      const float hv = sigf(go) * tanhf(cn);
      qs[c4 + j] = hv;
      pk |= (u64)f2b(hv) << (16 * j);
    }
    *(u64*)(Acat + (size_t)r * 2048 + Hh + c4) = pk;
  }
  __syncthreads();
  for (int sub = 0; sub < 16; ++sub) {
    const int ss = wave * 16 + sub;
    const ushort4* hp4 = (const ushort4*)(hxl + ((size_t)ss * Bb + b) * Hh);
    float p = 0.f;
#pragma unroll
    for (int q = 0; q < 4; ++q) {
      const int i4 = lane + 64 * q;
      const ushort4 v = hp4[i4];
      p += qs[i4 * 4 + 0] * b2f(v.x) + qs[i4 * 4 + 1] * b2f(v.y)
         + qs[i4 * 4 + 2] * b2f(v.z) + qs[i4 * 4 + 3] * b2f(v.w);
    }
#pragma unroll
    for (int d = 1; d < 64; d <<= 1) p += __shfl_xor(p, d, 64);
    if (lane == 0) sc[ss] = (src[b * 64 + ss] != 0) ? p : -INFINITY;
  }
  __syncthreads();
  if (wave == 0) {
    const float v = sc[lane];
    float m = v;
#pragma unroll
    for (int d = 1; d < 64; d <<= 1) m = fmaxf(m, __shfl_xor(m, d, 64));
    const float e = __expf(v - m);
    float ssum = e;
#pragma unroll
    for (int d = 1; d < 64; d <<= 1) ssum += __shfl_xor(ssum, d, 64);
    sc[lane] = e / ssum;
  }
  __syncthreads();
  float4 a4 = {0.f, 0.f, 0.f, 0.f};
  for (int s2 = 0; s2 < 64; ++s2) {
    const float a = sc[s2];
    const ushort4 v = *(const ushort4*)(hxl + ((size_t)s2 * Bb + b) * Hh + tid * 4);
    a4.x += a * b2f(v.x); a4.y += a * b2f(v.y);
    a4.z += a * b2f(v.z); a4.w += a * b2f(v.w);
  }
  u16* dst = Acat + (size_t)r * 2048 + tid * 4;
  dst[0] = f2b(a4.x); dst[1] = f2b(a4.y); dst[2] = f2b(a4.z); dst[3] = f2b(a4.w);
}

// ---- merged: lse combine + target logit -> nll[r] ----
__global__ void k_lsetl(const float* __restrict__ pmax, const float* __restrict__ psum,
                        const u16* __restrict__ hx_att_b, const int* __restrict__ target,
                        const float* __restrict__ W, const float* __restrict__ bo,
                        float* __restrict__ nll, int ncols) {
  const int r = blockIdx.x * 4 + (threadIdx.x >> 6);
  const int lane = threadIdx.x & 63;
  if (r >= RD) return;
  float m = -INFINITY;
  for (int i = lane; i < ncols; i += 64) m = fmaxf(m, pmax[(size_t)r * ncols + i]);
#pragma unroll
  for (int d = 1; d < 64; d <<= 1) m = fmaxf(m, __shfl_xor(m, d, 64));
  float s = 0.f;
  for (int i = lane; i < ncols; i += 64)
    s += psum[(size_t)r * ncols + i] * __expf(pmax[(size_t)r * ncols + i] - m);
#pragma unroll
  for (int d = 1; d < 64; d <<= 1) s += __shfl_xor(s, d, 64);
  const int t = r >> 6, b = r & 63;
  const int w = target[b * 64 + t + 1];
  const u16* a = hx_att_b + (size_t)r * Hh;
  const float* wr = W + (size_t)w * Hh;
  float p = 0.f;
  for (int h = lane; h < Hh; h += 64) p += b2f(a[h]) * wr[h];
#pragma unroll
  for (int d = 1; d < 64; d <<= 1) p += __shfl_xor(p, d, 64);
  if (lane == 0) nll[r] = (m + logf(s)) - (p + bo[w]);
}

// ---- final reduction -> scalar loss
__global__ void k_final(const float* __restrict__ nll, const int* __restrict__ target,
                        float* __restrict__ out) {
  const int t = threadIdx.x;
  float ps = 0.f;
  if (t < 63) {
    float sn = 0.f, cnt = 0.f;
    for (int b = 0; b < 64; ++b) {
      const int r = t * 64 + b;
      const int w = target[b * 64 + t + 1];
      if (w != 0) { sn += nll[r]; cnt += 1.f; }
    }
    ps = sn / fmaxf(cnt, 1.f);
  }
#pragma unroll
  for (int d = 1; d < 64; d <<= 1) ps += __shfl_xor(ps, d, 64);
  if (t == 0) out[0] = ps;
}

extern "C" void kernel_launch(void* const* d_in, const int* in_sizes, int n_in,
                              void* d_out, int out_size, void* d_ws, size_t ws_size,
                              hipStream_t stream) {
  const int*   source   = (const int*)d_in[0];
  const int*   target   = (const int*)d_in[1];
  const float* emb_src  = (const float*)d_in[2];
  const float* emb_tgt  = (const float*)d_in[3];
  const float* W_ih_enc = (const float*)d_in[4];
  const float* W_hh_enc = (const float*)d_in[5];
  const float* b_ih_enc = (const float*)d_in[6];
  const float* b_hh_enc = (const float*)d_in[7];
  const float* W_ih_dec = (const float*)d_in[8];
  const float* W_hh_dec = (const float*)d_in[9];
  const float* b_ih_dec = (const float*)d_in[10];
  const float* b_hh_dec = (const float*)d_in[11];
  const float* W_att    = (const float*)d_in[12];
  const float* b_att    = (const float*)d_in[13];
  const float* W_out    = (const float*)d_in[14];
  const float* b_out    = (const float*)d_in[15];
  float* out = (float*)d_out;

  char* base = (char*)d_ws;
  size_t off = 0;
  auto alloc = [&](size_t bytes) -> void* {
    void* r = base + off; off += (bytes + 255) & ~(size_t)255; return r;
  };
  u16*   wb_ih_enc = (u16*)alloc((size_t)NT4 * Hh * 2);
  u16*   wb_hh_enc = (u16*)alloc((size_t)NT4 * Hh * 2);
  u16*   wb_ih_dec = (u16*)alloc((size_t)NT4 * Hh * 2);
  u16*   wb_hh_dec = (u16*)alloc((size_t)NT4 * Hh * 2);
  u16*   wb_att    = (u16*)alloc((size_t)Hh * 2048 * 2);
  u16*   wb_out    = (u16*)alloc((size_t)Vv * Hh * 2);
  u16*   x_src_b   = (u16*)alloc((size_t)RP * Hh * 2);
  u16*   x_dec_b   = (u16*)alloc((size_t)RP * Hh * 2);
  u16*   gates16   = (u16*)alloc((size_t)RP * NT4 * 2);
  u16*   gates_dec = (u16*)alloc((size_t)RP * NT4 * 2);
  u16*   hxl       = (u16*)alloc((size_t)Ss * Bb * Hh * 2);
  float* c_enc     = (float*)alloc((size_t)Bb * Hh * 4);
  float* dbase     = (float*)alloc((size_t)64 * NT4 * 4);
  u16*   Acat      = (u16*)alloc((size_t)RP * 2048 * 2);
  u16*   hx_att_b  = (u16*)alloc((size_t)RP * Hh * 2);
  float* pmax      = (float*)alloc((size_t)RP * 500 * 4);
  float* psum      = (float*)alloc((size_t)RP * 500 * 4);
  float* nll       = (float*)alloc((size_t)RD * 4);
  int*   flags     = (int*)alloc(ENC_NBLK * ENC_NBLK * 4);

  if (off > ws_size) { k_fail<<<1, 1, 0, stream>>>(out); return; }

  // weights -> bf16 + both embedding gathers + flags zero (one launch)
  k_prep<<<2048 + 2 * RP + 1, 256, 0, stream>>>(W_ih_enc, wb_ih_enc, W_hh_enc, wb_hh_enc,
                                                W_ih_dec, wb_ih_dec, W_hh_dec, wb_hh_dec,
                                                W_att, wb_att, W_out, wb_out,
                                                source, emb_src, x_src_b,
                                                target, emb_tgt, x_dec_b, flags);

  // enc + dec x-gate pre-GEMMs (one launch, 8-phase 256^2)
  k_vg_pre<<<512, 512, 0, stream>>>(x_src_b, wb_ih_enc, gates16,
                                    x_dec_b, wb_ih_dec, gates_dec);

  // persistent dataflow encoder + fused dbase epilogue
  k_enc_all<<<ENC_NBLK, 256, 0, stream>>>(wb_hh_enc, gates16, b_ih_enc, b_hh_enc,
                                          hxl, c_enc, flags, wb_hh_dec, dbase);

  // fused decoder cell + attention -> Acat[:,H..] and Acat[:, :H]
  k_dattn<<<RD, 256, 0, stream>>>(Acat, hxl, source, gates_dec, dbase, c_enc,
                                  b_ih_dec, b_hh_dec);

  // hx_att_b = bf16(tanh(A_cat @ W_att^T + b_att)) on 8-phase template (K=2048)
  k_attgemm<<<64, 512, 0, stream>>>(Acat, wb_att, b_att, hx_att_b);

  // vocab GEMM (8-phase 256^2 + T2 swizzle) with fused lse partials
  k_vgemm<<<2000, 512, 0, stream>>>(hx_att_b, wb_out, b_out, pmax, psum);
  k_lsetl<<<(RD + 3) / 4, 256, 0, stream>>>(pmax, psum, hx_att_b, target, W_out, b_out,
                                            nll, 500);
  k_final<<<1, 64, 0, stream>>>(nll, target, out);
}